// Round 18
// baseline (321.827 us; speedup 1.0000x reference)
//
#include <hip/hip_runtime.h>
#include <hip/hip_bf16.h>

// ARMANet: 2x ARMAConv(K=1,T=1) + global mean pool + FC
// N=100000 nodes, E=1600000 edges, IN=HID=64, OUT=32, G=64 graphs.
// R18: R14 config (best: 293 us) + dispatch-count reduction:
//      - wprep merged into bucket_kernel (branch on blockIdx)
//      - final_fc merged into pool_kernel (last-block pattern, device-scope
//        atomic counter; pooled re-read via atomicAdd(p,0) for XCD coherence)
//      11 dispatches -> 8. gemm epilogue = R14 plain ushort stores.

#define NB 256
#define CAP 5120
#define MAXB 400
#define P1_CHUNK 2048

typedef unsigned int uint32;
typedef unsigned short ushort16;
typedef __attribute__((ext_vector_type(8))) short short8;   // 8 bf16 (4 VGPRs)
typedef __attribute__((ext_vector_type(4))) float f32x4;    // MFMA C/D

__device__ inline uint32 bf16rn(float f) {
    uint32 u = __float_as_uint(f);
    uint32 r = ((u >> 16) & 1u) + 0x7FFFu;
    return (u + r) >> 16;
}
__device__ inline uint32 pack_bf16(float a, float b) {
    return bf16rn(a) | (bf16rn(b) << 16);
}
__device__ inline float bflo(uint32 u) { return __uint_as_float(u << 16); }
__device__ inline float bfhi(uint32 u) { return __uint_as_float(u & 0xFFFF0000u); }

// ---------------- stage 1: bucket edges by destination (+ merged wprep) ----------------
// Blocks [0, EB): bucket edges. Blocks [EB, EB+128): weight prep (8*4096 elems).
__global__ __launch_bounds__(256) void bucket_kernel(
    const int* __restrict__ row, const int* __restrict__ col,
    uint32* __restrict__ bpack, int* __restrict__ bcnt, int E, int EB,
    const float* __restrict__ W1i, const float* __restrict__ W1r,
    const float* __restrict__ W2i, const float* __restrict__ W2r,
    ushort16* __restrict__ wt) {
    int t = threadIdx.x;

    if (blockIdx.x >= EB) {
        // ---- wprep: weights -> transposed split-bf16 table wt[m][d*64+k] ----
        int idx = (blockIdx.x - EB) * 256 + t;
        if (idx < 8 * 4096) {
            int m = idx >> 12;
            int r = idx & 4095;
            int d = r >> 6, k = r & 63;
            const float* W = (m < 2) ? W1i : (m < 4) ? W1r : (m < 6) ? W2i : W2r;
            float v = W[k * 64 + d];
            uint32 hi = bf16rn(v);
            uint32 outv;
            if (m & 1) {
                float hf = __uint_as_float(hi << 16);
                outv = bf16rn(v - hf);
            } else {
                outv = hi;
            }
            wt[(size_t)m * 4096 + d * 64 + k] = (unsigned short)outv;
        }
        return;
    }

    __shared__ int hist[MAXB];
    __shared__ int ofs[MAXB];
    __shared__ int cur[MAXB];
    __shared__ int gbase[MAXB];
    __shared__ int s[256];
    __shared__ uint32 stage[P1_CHUNK];
    __shared__ unsigned short stage_bk[P1_CHUNK];

    for (int i = t; i < MAXB; i += 256) hist[i] = 0;
    __syncthreads();

    int e0 = blockIdx.x * P1_CHUNK;
    int cntE = min(E - e0, P1_CHUNK);

    for (int i = t; i < cntE; i += 256) {
        int c = col[e0 + i];
        atomicAdd(&hist[c >> 8], 1);
    }
    __syncthreads();

    int i2 = 2 * t;
    int a = (i2 < MAXB) ? hist[i2] : 0;
    int b = (i2 + 1 < MAXB) ? hist[i2 + 1] : 0;
    s[t] = a + b;
    __syncthreads();
    for (int off = 1; off < 256; off <<= 1) {
        int x = (t >= off) ? s[t - off] : 0;
        __syncthreads();
        s[t] += x;
        __syncthreads();
    }
    int excl = (t > 0) ? s[t - 1] : 0;
    if (i2 < MAXB) ofs[i2] = excl;
    if (i2 + 1 < MAXB) ofs[i2 + 1] = excl + a;
    __syncthreads();

    for (int i = t; i < MAXB; i += 256) {
        cur[i] = ofs[i];
        gbase[i] = hist[i] ? atomicAdd(&bcnt[i], hist[i]) : 0;
    }
    __syncthreads();

    for (int i = t; i < cntE; i += 256) {
        int c = col[e0 + i];
        int r = row[e0 + i];
        int bk = c >> 8;
        int k = atomicAdd(&cur[bk], 1);
        stage[k] = ((uint32)(c & 255) << 24) | (uint32)r;
        stage_bk[k] = (unsigned short)bk;
    }
    __syncthreads();

    for (int i = t; i < cntE; i += 256) {
        uint32 pk = stage[i];
        int bk = stage_bk[i];
        int gd = gbase[bk] + (i - ofs[bk]);
        if (gd < CAP) bpack[(size_t)bk * CAP + gd] = pk;
    }
}

// ---------------- stage 2: per-bucket counting sort -> CSR + dinv ----------------
__global__ __launch_bounds__(1024) void csr_kernel(
    const uint32* __restrict__ bpack, const int* __restrict__ bcnt,
    int* __restrict__ es, int* __restrict__ nstart, int* __restrict__ ndeg,
    float* __restrict__ dinv, int n) {
    __shared__ uint32 sbp[CAP];   // 20 KB
    __shared__ int h[NB];
    __shared__ int s[NB];
    __shared__ int cur[NB];
    int b = blockIdx.x, t = threadIdx.x;
    if (t < NB) h[t] = 0;
    __syncthreads();
    int cnt = min(bcnt[b], CAP);
    size_t base = (size_t)b * CAP;
    for (int i = t; i < cnt; i += 1024) {
        uint32 pk = bpack[base + i];
        sbp[i] = pk;
        atomicAdd(&h[pk >> 24], 1);
    }
    __syncthreads();
    if (t < NB) s[t] = h[t];
    __syncthreads();
    for (int off = 1; off < NB; off <<= 1) {
        int x = 0;
        if (t < NB && t >= off) x = s[t - off];
        __syncthreads();
        if (t < NB) s[t] += x;
        __syncthreads();
    }
    if (t < NB) {
        int myofs = s[t] - h[t];
        cur[t] = myofs;
        int node = b * NB + t;
        if (node < n) {
            nstart[node] = (int)base + myofs;
            ndeg[node] = h[t];
            dinv[node] = h[t] ? rsqrtf((float)h[t]) : 0.0f;
        }
    }
    __syncthreads();
    for (int i = t; i < cnt; i += 1024) {
        uint32 pk = sbp[i];
        int cl = (int)(pk >> 24);
        int p = atomicAdd(&cur[cl], 1);
        es[base + p] = (int)(pk & 0xFFFFFFu);
    }
}

// ---------------- MFMA dual GEMM (LDS-staged A, R14 epilogue) ----------------
// Ts = bf16(dinv .* (X@Winit)), Rs = bf16(X@Wroot + bias).
// X: f32 (xf32=1, layer 1) or packed bf16 uint rows (xf32=0, layer 2).
__global__ __launch_bounds__(256) void gemm_mfma(
    const void* __restrict__ Xin,
    const ushort16* __restrict__ wt4,         // 4 mats: init_hi, init_lo, root_hi, root_lo
    const float* __restrict__ bias, const float* __restrict__ dinv,
    ushort16* __restrict__ Ts, ushort16* __restrict__ Rs, int n, int xf32) {
    __shared__ unsigned short sXs[64 * 72];   // 9216 B, row stride 72 bf16
    int t = threadIdx.x;
    int node0 = blockIdx.x * 64;

    if (xf32) {
        const float* X = (const float*)Xin;
        for (int i = t; i < 1024; i += 256) {
            int r = i >> 4, c4 = (i & 15) * 4;
            int node = node0 + r;
            float4 v = make_float4(0.f, 0.f, 0.f, 0.f);
            if (node < n) v = *(const float4*)&X[(size_t)node * 64 + c4];
            *(uint32*)&sXs[r * 72 + c4] = pack_bf16(v.x, v.y);
            *(uint32*)&sXs[r * 72 + c4 + 2] = pack_bf16(v.z, v.w);
        }
    } else {
        const uint32* Xb2 = (const uint32*)Xin;
        for (int i = t; i < 512; i += 256) {
            int r = i >> 3, kg = i & 7;
            int node = node0 + r;
            uint4 v = make_uint4(0u, 0u, 0u, 0u);
            if (node < n) v = *(const uint4*)&Xb2[(size_t)node * 32 + kg * 4];
            *(uint4*)&sXs[r * 72 + kg * 8] = v;
        }
    }

    int w = t >> 6;
    int lane = t & 63;
    int q = lane >> 4;
    int col = lane & 15;
    int dim = w * 16 + col;

    // B fragments from precomputed table (16 B loads, L2-hot)
    short8 bih[2], bil[2], brh[2], brl[2];
#pragma unroll
    for (int kh = 0; kh < 2; ++kh) {
        size_t o = (size_t)dim * 64 + kh * 32 + q * 8;
        bih[kh] = *(const short8*)&wt4[0 * 4096 + o];
        bil[kh] = *(const short8*)&wt4[1 * 4096 + o];
        brh[kh] = *(const short8*)&wt4[2 * 4096 + o];
        brl[kh] = *(const short8*)&wt4[3 * 4096 + o];
    }
    float bi = bias[dim];
    __syncthreads();

#pragma unroll
    for (int mt = 0; mt < 4; ++mt) {
        int rbase = mt * 16 + col;
        short8 a0 = *(const short8*)&sXs[rbase * 72 + q * 8];
        short8 a1 = *(const short8*)&sXs[rbase * 72 + 32 + q * 8];
        f32x4 accT = {0.f, 0.f, 0.f, 0.f};
        f32x4 accR = {0.f, 0.f, 0.f, 0.f};
        accT = __builtin_amdgcn_mfma_f32_16x16x32_bf16(a0, bih[0], accT, 0, 0, 0);
        accT = __builtin_amdgcn_mfma_f32_16x16x32_bf16(a1, bih[1], accT, 0, 0, 0);
        accT = __builtin_amdgcn_mfma_f32_16x16x32_bf16(a0, bil[0], accT, 0, 0, 0);
        accT = __builtin_amdgcn_mfma_f32_16x16x32_bf16(a1, bil[1], accT, 0, 0, 0);
        accR = __builtin_amdgcn_mfma_f32_16x16x32_bf16(a0, brh[0], accR, 0, 0, 0);
        accR = __builtin_amdgcn_mfma_f32_16x16x32_bf16(a1, brh[1], accR, 0, 0, 0);
        accR = __builtin_amdgcn_mfma_f32_16x16x32_bf16(a0, brl[0], accR, 0, 0, 0);
        accR = __builtin_amdgcn_mfma_f32_16x16x32_bf16(a1, brl[1], accR, 0, 0, 0);
#pragma unroll
        for (int reg = 0; reg < 4; ++reg) {
            int node = node0 + mt * 16 + q * 4 + reg;
            if (node < n) {
                float dv = dinv[node];
                Ts[(size_t)node * 64 + dim] = (unsigned short)bf16rn(accT[reg] * dv);
                Rs[(size_t)node * 64 + dim] = (unsigned short)bf16rn(accR[reg] + bi);
            }
        }
    }
}

// ---------------- fused gather-propagate + relu: 4 edges per wave, uint2 loads ----------------
__global__ __launch_bounds__(256) void gather_fused(
    const uint2* __restrict__ Ts2, const uint2* __restrict__ Rs2,
    const int* __restrict__ es, const int* __restrict__ nstart,
    const int* __restrict__ ndeg, const float* __restrict__ dinv,
    uint2* __restrict__ Hb2, int n) {
    int c = blockIdx.x * 4 + (threadIdx.x >> 6);
    if (c >= n) return;
    int lane = threadIdx.x & 63;
    int q = lane >> 4;    // edge slot 0..3
    int d4 = lane & 15;   // dim quad
    int deg = ndeg[c];
    int s0 = nstart[c];
    float a0 = 0.f, a1 = 0.f, a2 = 0.f, a3 = 0.f;
    for (int base = 0; base < deg; base += 64) {
        int m = min(deg - base, 64);
        int sid = (lane < m) ? es[s0 + base + lane] : 0;
        for (int j = 0; j < m; j += 16) {
            int e0 = j + q, e1 = j + 4 + q, e2 = j + 8 + q, e3 = j + 12 + q;
            int r0 = __shfl(sid, e0);
            int r1 = __shfl(sid, e1);
            int r2 = __shfl(sid, e2);
            int r3 = __shfl(sid, e3);
            uint2 z = make_uint2(0u, 0u);
            uint2 v0 = (e0 < m) ? Ts2[(size_t)r0 * 16 + d4] : z;
            uint2 v1 = (e1 < m) ? Ts2[(size_t)r1 * 16 + d4] : z;
            uint2 v2 = (e2 < m) ? Ts2[(size_t)r2 * 16 + d4] : z;
            uint2 v3 = (e3 < m) ? Ts2[(size_t)r3 * 16 + d4] : z;
            a0 += bflo(v0.x) + bflo(v1.x) + bflo(v2.x) + bflo(v3.x);
            a1 += bfhi(v0.x) + bfhi(v1.x) + bfhi(v2.x) + bfhi(v3.x);
            a2 += bflo(v0.y) + bflo(v1.y) + bflo(v2.y) + bflo(v3.y);
            a3 += bfhi(v0.y) + bfhi(v1.y) + bfhi(v2.y) + bfhi(v3.y);
        }
    }
    a0 += __shfl_xor(a0, 16); a0 += __shfl_xor(a0, 32);
    a1 += __shfl_xor(a1, 16); a1 += __shfl_xor(a1, 32);
    a2 += __shfl_xor(a2, 16); a2 += __shfl_xor(a2, 32);
    a3 += __shfl_xor(a3, 16); a3 += __shfl_xor(a3, 32);
    if (lane < 16) {
        float dc = dinv[c];
        uint2 ur = Rs2[(size_t)c * 16 + d4];
        float h0 = fmaxf(fmaf(dc, a0, bflo(ur.x)), 0.0f);
        float h1 = fmaxf(fmaf(dc, a1, bfhi(ur.x)), 0.0f);
        float h2 = fmaxf(fmaf(dc, a2, bflo(ur.y)), 0.0f);
        float h3 = fmaxf(fmaf(dc, a3, bfhi(ur.y)), 0.0f);
        Hb2[(size_t)c * 16 + d4] = make_uint2(pack_bf16(h0, h1), pack_bf16(h2, h3));
    }
}

// ---------------- mean-pool + fused final FC (last-block pattern) ----------------
__global__ __launch_bounds__(256) void pool_fc_kernel(
    const uint32* __restrict__ Hb, const int* __restrict__ batch,
    float* __restrict__ pooled, float* __restrict__ cnt, int* __restrict__ done,
    const float* __restrict__ fcw, const float* __restrict__ fcb,
    float* __restrict__ out, int n, int nblocks) {
    __shared__ float sAcc[64 * 64];
    __shared__ float sCnt[64];
    __shared__ int amLast;
    int tid = threadIdx.x;
    for (int i = tid; i < 4096; i += 256) sAcc[i] = 0.0f;
    if (tid < 64) sCnt[tid] = 0.0f;
    __syncthreads();

    int w = tid >> 6, lane = tid & 63;
    int half = lane >> 5, d2 = lane & 31;
    int s = blockIdx.x * 256 + w * 64;
    int e = min(s + 64, n);
    float a0 = 0.0f, a1 = 0.0f, c = 0.0f;
    int gcur = -1;
    for (int i = s + half; i < e; i += 2) {
        int g = batch[i];
        if (g != gcur) {
            if (gcur >= 0) {
                atomicAdd(&sAcc[gcur * 64 + 2 * d2], a0);
                atomicAdd(&sAcc[gcur * 64 + 2 * d2 + 1], a1);
                if (d2 == 0) atomicAdd(&sCnt[gcur], c);
            }
            gcur = g; a0 = 0.0f; a1 = 0.0f; c = 0.0f;
        }
        uint32 u = Hb[(size_t)i * 32 + d2];
        a0 += bflo(u);
        a1 += bfhi(u);
        c += 1.0f;
    }
    if (gcur >= 0) {
        atomicAdd(&sAcc[gcur * 64 + 2 * d2], a0);
        atomicAdd(&sAcc[gcur * 64 + 2 * d2 + 1], a1);
        if (d2 == 0) atomicAdd(&sCnt[gcur], c);
    }
    __syncthreads();
    for (int i = tid; i < 4096; i += 256) {
        float v = sAcc[i];
        if (v != 0.0f) atomicAdd(&pooled[i], v);
    }
    if (tid < 64) {
        float v = sCnt[tid];
        if (v != 0.0f) atomicAdd(&cnt[tid], v);
    }

    // last-block: fold in FC
    __threadfence();
    __syncthreads();
    if (tid == 0) amLast = (atomicAdd(done, 1) == nblocks - 1);
    __syncthreads();
    if (!amLast) return;

    // re-read pooled/cnt with device-scope atomics (XCD-coherent), reuse sAcc/sCnt
    for (int i = tid; i < 4096; i += 256) sAcc[i] = atomicAdd(&pooled[i], 0.0f);
    if (tid < 64) sCnt[tid] = atomicAdd(&cnt[tid], 0.0f);
    __syncthreads();
    for (int idx = tid; idx < 64 * 32; idx += 256) {
        int g = idx >> 5, o = idx & 31;
        float cc = fmaxf(sCnt[g], 1.0f);
        float acc = 0.0f;
#pragma unroll
        for (int k = 0; k < 64; ++k) acc = fmaf(sAcc[g * 64 + k], fcw[k * 32 + o], acc);
        out[idx] = acc / cc + fcb[o];
    }
}

extern "C" void kernel_launch(void* const* d_in, const int* in_sizes, int n_in,
                              void* d_out, int out_size, void* d_ws, size_t ws_size,
                              hipStream_t stream) {
    const float* x       = (const float*)d_in[0];
    const int*   eidx    = (const int*)d_in[1];
    const int*   batch   = (const int*)d_in[2];
    const float* w1_init = (const float*)d_in[3];
    const float* w1_root = (const float*)d_in[4];
    const float* b1      = (const float*)d_in[5];
    const float* w2_init = (const float*)d_in[6];
    const float* w2_root = (const float*)d_in[7];
    const float* b2      = (const float*)d_in[8];
    const float* fc_w    = (const float*)d_in[9];
    const float* fc_b    = (const float*)d_in[10];
    float* out = (float*)d_out;

    const int N = in_sizes[0] / 64;
    const int E = in_sizes[1] / 2;
    const int* row = eidx;
    const int* col = eidx + E;

    const int B = (N + NB - 1) / NB;            // 391 buckets
    const int EB = (E + P1_CHUNK - 1) / P1_CHUNK;  // 782 bucket blocks
    const int WB = (8 * 4096) / 256;            // 128 wprep blocks

    // workspace (4-byte units, 16B-aligned chunks):
    // bpack(B*CAP) | es(B*CAP) | bcnt(MAXB) | pooled(4096) | cnt(64) | done(4)
    // | nstart(N) | ndeg(N) | dinv(N) | wt(16384 uints = 8 mats * 4096 ushorts)
    // | Ts(N*32) | Rs(N*32) | Hb(N*32)
    uint32* bpack = (uint32*)d_ws;
    int*   es     = (int*)(bpack + (size_t)B * CAP);
    int*   bcnt   = es + (size_t)B * CAP;
    float* pooled = (float*)(bcnt + MAXB);
    float* cnt    = pooled + 64 * 64;
    int*   done   = (int*)(cnt + 64);               // +4 ints (done + pad)
    int*   nstart = done + 4;
    int*   ndeg   = nstart + N;
    float* dinv   = (float*)(ndeg + N);
    uint32* wtU   = (uint32*)(dinv + N);            // 16384 uints (64 KB)
    uint32* Ts    = wtU + 16384;                    // N*32
    uint32* Rs    = Ts + (size_t)N * 32;            // N*32
    uint32* Hb    = Rs + (size_t)N * 32;            // N*32
    ushort16* wt  = (ushort16*)wtU;

    // zero: bcnt + pooled + cnt + done
    hipMemsetAsync(bcnt, 0, (size_t)(MAXB + 64 * 64 + 64 + 4) * sizeof(int), stream);

    // CSR build + weight prep (merged grid)
    bucket_kernel<<<EB + WB, 256, 0, stream>>>(row, col, bpack, bcnt, E, EB,
                                               w1_init, w1_root, w2_init, w2_root, wt);
    csr_kernel<<<B, 1024, 0, stream>>>(bpack, bcnt, es, nstart, ndeg, dinv, N);

    // layer 1 (f32 input); wt = mats 0..3
    gemm_mfma<<<(N + 63) / 64, 256, 0, stream>>>(x, wt, b1, dinv,
                                                 (ushort16*)Ts, (ushort16*)Rs, N, 1);
    gather_fused<<<(N + 3) / 4, 256, 0, stream>>>((const uint2*)Ts, (const uint2*)Rs,
                                                  es, nstart, ndeg, dinv, (uint2*)Hb, N);

    // layer 2 (bf16 input); wt + 4*4096 ushorts = mats 4..7
    gemm_mfma<<<(N + 63) / 64, 256, 0, stream>>>(Hb, wt + (size_t)4 * 4096, b2, dinv,
                                                 (ushort16*)Ts, (ushort16*)Rs, N, 0);
    gather_fused<<<(N + 3) / 4, 256, 0, stream>>>((const uint2*)Ts, (const uint2*)Rs,
                                                  es, nstart, ndeg, dinv, (uint2*)Hb, N);

    // pool + FC (fused, last-block)
    const int PB = (N + 255) / 256;
    pool_fc_kernel<<<PB, 256, 0, stream>>>(Hb, batch, pooled, cnt, done,
                                           fc_w, fc_b, out, N, PB);
}

// Round 19
// 292.584 us; speedup vs baseline: 1.0999x; 1.0999x over previous
//
#include <hip/hip_runtime.h>
#include <hip/hip_bf16.h>

// ARMANet: 2x ARMAConv(K=1,T=1) + global mean pool + FC
// N=100000 nodes, E=1600000 edges, IN=HID=64, OUT=32, G=64 graphs.
// R19 = R14 exact revert (best measured: 293.0 us). Final configuration:
//  - bucketed edge multi-split (2048-edge chunks, LDS stage, contiguous writes)
//  - per-bucket counting sort -> CSR + dinv (LDS-cached, no global f32 atomics)
//  - MFMA dual GEMM (16x16x32 bf16, split-bf16 weights, LDS-staged A tile)
//  - gather-propagate at the LLC random-line-fetch floor (uint2 bf16 rows,
//    4 edges/wave, shfl_xor reduction), relu fused, bf16 H
//  - register-accumulating pool over sorted batch + tiny FC.

#define NB 256
#define CAP 5120
#define MAXB 400
#define P1_CHUNK 2048

typedef unsigned int uint32;
typedef unsigned short ushort16;
typedef __attribute__((ext_vector_type(8))) short short8;   // 8 bf16 (4 VGPRs)
typedef __attribute__((ext_vector_type(4))) float f32x4;    // MFMA C/D

__device__ inline uint32 bf16rn(float f) {
    uint32 u = __float_as_uint(f);
    uint32 r = ((u >> 16) & 1u) + 0x7FFFu;
    return (u + r) >> 16;
}
__device__ inline uint32 pack_bf16(float a, float b) {
    return bf16rn(a) | (bf16rn(b) << 16);
}
__device__ inline float bflo(uint32 u) { return __uint_as_float(u << 16); }
__device__ inline float bfhi(uint32 u) { return __uint_as_float(u & 0xFFFF0000u); }

// ---------------- stage 1: bucket edges by destination ----------------
__global__ __launch_bounds__(256) void bucket_kernel(
    const int* __restrict__ row, const int* __restrict__ col,
    uint32* __restrict__ bpack, int* __restrict__ bcnt, int E) {
    __shared__ int hist[MAXB];
    __shared__ int ofs[MAXB];
    __shared__ int cur[MAXB];
    __shared__ int gbase[MAXB];
    __shared__ int s[256];
    __shared__ uint32 stage[P1_CHUNK];
    __shared__ unsigned short stage_bk[P1_CHUNK];

    int t = threadIdx.x;
    for (int i = t; i < MAXB; i += 256) hist[i] = 0;
    __syncthreads();

    int e0 = blockIdx.x * P1_CHUNK;
    int cntE = min(E - e0, P1_CHUNK);

    for (int i = t; i < cntE; i += 256) {
        int c = col[e0 + i];
        atomicAdd(&hist[c >> 8], 1);
    }
    __syncthreads();

    int i2 = 2 * t;
    int a = (i2 < MAXB) ? hist[i2] : 0;
    int b = (i2 + 1 < MAXB) ? hist[i2 + 1] : 0;
    s[t] = a + b;
    __syncthreads();
    for (int off = 1; off < 256; off <<= 1) {
        int x = (t >= off) ? s[t - off] : 0;
        __syncthreads();
        s[t] += x;
        __syncthreads();
    }
    int excl = (t > 0) ? s[t - 1] : 0;
    if (i2 < MAXB) ofs[i2] = excl;
    if (i2 + 1 < MAXB) ofs[i2 + 1] = excl + a;
    __syncthreads();

    for (int i = t; i < MAXB; i += 256) {
        cur[i] = ofs[i];
        gbase[i] = hist[i] ? atomicAdd(&bcnt[i], hist[i]) : 0;
    }
    __syncthreads();

    for (int i = t; i < cntE; i += 256) {
        int c = col[e0 + i];
        int r = row[e0 + i];
        int bk = c >> 8;
        int k = atomicAdd(&cur[bk], 1);
        stage[k] = ((uint32)(c & 255) << 24) | (uint32)r;
        stage_bk[k] = (unsigned short)bk;
    }
    __syncthreads();

    for (int i = t; i < cntE; i += 256) {
        uint32 pk = stage[i];
        int bk = stage_bk[i];
        int gd = gbase[bk] + (i - ofs[bk]);
        if (gd < CAP) bpack[(size_t)bk * CAP + gd] = pk;
    }
}

// ---------------- stage 2: per-bucket counting sort -> CSR + dinv ----------------
__global__ __launch_bounds__(1024) void csr_kernel(
    const uint32* __restrict__ bpack, const int* __restrict__ bcnt,
    int* __restrict__ es, int* __restrict__ nstart, int* __restrict__ ndeg,
    float* __restrict__ dinv, int n) {
    __shared__ uint32 sbp[CAP];   // 20 KB
    __shared__ int h[NB];
    __shared__ int s[NB];
    __shared__ int cur[NB];
    int b = blockIdx.x, t = threadIdx.x;
    if (t < NB) h[t] = 0;
    __syncthreads();
    int cnt = min(bcnt[b], CAP);
    size_t base = (size_t)b * CAP;
    for (int i = t; i < cnt; i += 1024) {
        uint32 pk = bpack[base + i];
        sbp[i] = pk;
        atomicAdd(&h[pk >> 24], 1);
    }
    __syncthreads();
    if (t < NB) s[t] = h[t];
    __syncthreads();
    for (int off = 1; off < NB; off <<= 1) {
        int x = 0;
        if (t < NB && t >= off) x = s[t - off];
        __syncthreads();
        if (t < NB) s[t] += x;
        __syncthreads();
    }
    if (t < NB) {
        int myofs = s[t] - h[t];
        cur[t] = myofs;
        int node = b * NB + t;
        if (node < n) {
            nstart[node] = (int)base + myofs;
            ndeg[node] = h[t];
            dinv[node] = h[t] ? rsqrtf((float)h[t]) : 0.0f;
        }
    }
    __syncthreads();
    for (int i = t; i < cnt; i += 1024) {
        uint32 pk = sbp[i];
        int cl = (int)(pk >> 24);
        int p = atomicAdd(&cur[cl], 1);
        es[base + p] = (int)(pk & 0xFFFFFFu);
    }
}

// ---------------- weights -> transposed split-bf16 table wt[m][d*64+k] ----------------
// m: 0=init_hi 1=init_lo 2=root_hi 3=root_lo (x2 layers -> 8 mats).
__global__ __launch_bounds__(256) void wprep_kernel(
    const float* __restrict__ W1i, const float* __restrict__ W1r,
    const float* __restrict__ W2i, const float* __restrict__ W2r,
    ushort16* __restrict__ wt) {
    int idx = blockIdx.x * 256 + threadIdx.x;  // 8*4096
    if (idx >= 8 * 4096) return;
    int m = idx >> 12;
    int r = idx & 4095;
    int d = r >> 6, k = r & 63;
    const float* W = (m < 2) ? W1i : (m < 4) ? W1r : (m < 6) ? W2i : W2r;
    float v = W[k * 64 + d];
    uint32 hi = bf16rn(v);
    uint32 outv;
    if (m & 1) {
        float hf = __uint_as_float(hi << 16);
        outv = bf16rn(v - hf);
    } else {
        outv = hi;
    }
    wt[(size_t)m * 4096 + d * 64 + k] = (unsigned short)outv;
}

// ---------------- MFMA dual GEMM (fused f32->bf16 X staging) ----------------
// Ts = bf16(dinv .* (X@Winit)), Rs = bf16(X@Wroot + bias).
// X: f32 (xf32=1, layer 1) or packed bf16 uint rows (xf32=0, layer 2).
__global__ __launch_bounds__(256) void gemm_mfma(
    const void* __restrict__ Xin,
    const ushort16* __restrict__ wt4,         // 4 mats: init_hi, init_lo, root_hi, root_lo
    const float* __restrict__ bias, const float* __restrict__ dinv,
    ushort16* __restrict__ Ts, ushort16* __restrict__ Rs, int n, int xf32) {
    __shared__ unsigned short sXs[64 * 72];   // 9216 B, row stride 72 bf16
    int t = threadIdx.x;
    int node0 = blockIdx.x * 64;

    if (xf32) {
        const float* X = (const float*)Xin;
        for (int i = t; i < 1024; i += 256) {
            int r = i >> 4, c4 = (i & 15) * 4;
            int node = node0 + r;
            float4 v = make_float4(0.f, 0.f, 0.f, 0.f);
            if (node < n) v = *(const float4*)&X[(size_t)node * 64 + c4];
            *(uint32*)&sXs[r * 72 + c4] = pack_bf16(v.x, v.y);
            *(uint32*)&sXs[r * 72 + c4 + 2] = pack_bf16(v.z, v.w);
        }
    } else {
        const uint32* Xb2 = (const uint32*)Xin;
        for (int i = t; i < 512; i += 256) {
            int r = i >> 3, kg = i & 7;
            int node = node0 + r;
            uint4 v = make_uint4(0u, 0u, 0u, 0u);
            if (node < n) v = *(const uint4*)&Xb2[(size_t)node * 32 + kg * 4];
            *(uint4*)&sXs[r * 72 + kg * 8] = v;
        }
    }

    int w = t >> 6;
    int lane = t & 63;
    int q = lane >> 4;
    int col = lane & 15;
    int dim = w * 16 + col;

    // B fragments from precomputed table (16 B loads, L2-hot)
    short8 bih[2], bil[2], brh[2], brl[2];
#pragma unroll
    for (int kh = 0; kh < 2; ++kh) {
        size_t o = (size_t)dim * 64 + kh * 32 + q * 8;
        bih[kh] = *(const short8*)&wt4[0 * 4096 + o];
        bil[kh] = *(const short8*)&wt4[1 * 4096 + o];
        brh[kh] = *(const short8*)&wt4[2 * 4096 + o];
        brl[kh] = *(const short8*)&wt4[3 * 4096 + o];
    }
    float bi = bias[dim];
    __syncthreads();

#pragma unroll
    for (int mt = 0; mt < 4; ++mt) {
        int rbase = mt * 16 + col;
        short8 a0 = *(const short8*)&sXs[rbase * 72 + q * 8];
        short8 a1 = *(const short8*)&sXs[rbase * 72 + 32 + q * 8];
        f32x4 accT = {0.f, 0.f, 0.f, 0.f};
        f32x4 accR = {0.f, 0.f, 0.f, 0.f};
        accT = __builtin_amdgcn_mfma_f32_16x16x32_bf16(a0, bih[0], accT, 0, 0, 0);
        accT = __builtin_amdgcn_mfma_f32_16x16x32_bf16(a1, bih[1], accT, 0, 0, 0);
        accT = __builtin_amdgcn_mfma_f32_16x16x32_bf16(a0, bil[0], accT, 0, 0, 0);
        accT = __builtin_amdgcn_mfma_f32_16x16x32_bf16(a1, bil[1], accT, 0, 0, 0);
        accR = __builtin_amdgcn_mfma_f32_16x16x32_bf16(a0, brh[0], accR, 0, 0, 0);
        accR = __builtin_amdgcn_mfma_f32_16x16x32_bf16(a1, brh[1], accR, 0, 0, 0);
        accR = __builtin_amdgcn_mfma_f32_16x16x32_bf16(a0, brl[0], accR, 0, 0, 0);
        accR = __builtin_amdgcn_mfma_f32_16x16x32_bf16(a1, brl[1], accR, 0, 0, 0);
#pragma unroll
        for (int reg = 0; reg < 4; ++reg) {
            int node = node0 + mt * 16 + q * 4 + reg;
            if (node < n) {
                float dv = dinv[node];
                Ts[(size_t)node * 64 + dim] = (unsigned short)bf16rn(accT[reg] * dv);
                Rs[(size_t)node * 64 + dim] = (unsigned short)bf16rn(accR[reg] + bi);
            }
        }
    }
}

// ---------------- fused gather-propagate + relu: 4 edges per wave, uint2 loads ----------------
// Quarter q = lane>>4 handles edges {j+q, j+4+q, j+8+q, j+12+q}; lane covers
// dims [4*d4, 4*d4+4) via 8B load. Cross-quarter shfl_xor(16/32) reduction.
__global__ __launch_bounds__(256) void gather_fused(
    const uint2* __restrict__ Ts2, const uint2* __restrict__ Rs2,
    const int* __restrict__ es, const int* __restrict__ nstart,
    const int* __restrict__ ndeg, const float* __restrict__ dinv,
    uint2* __restrict__ Hb2, int n) {
    int c = blockIdx.x * 4 + (threadIdx.x >> 6);
    if (c >= n) return;
    int lane = threadIdx.x & 63;
    int q = lane >> 4;    // edge slot 0..3
    int d4 = lane & 15;   // dim quad
    int deg = ndeg[c];
    int s0 = nstart[c];
    float a0 = 0.f, a1 = 0.f, a2 = 0.f, a3 = 0.f;
    for (int base = 0; base < deg; base += 64) {
        int m = min(deg - base, 64);
        int sid = (lane < m) ? es[s0 + base + lane] : 0;
        for (int j = 0; j < m; j += 16) {
            int e0 = j + q, e1 = j + 4 + q, e2 = j + 8 + q, e3 = j + 12 + q;
            int r0 = __shfl(sid, e0);
            int r1 = __shfl(sid, e1);
            int r2 = __shfl(sid, e2);
            int r3 = __shfl(sid, e3);
            uint2 z = make_uint2(0u, 0u);
            uint2 v0 = (e0 < m) ? Ts2[(size_t)r0 * 16 + d4] : z;
            uint2 v1 = (e1 < m) ? Ts2[(size_t)r1 * 16 + d4] : z;
            uint2 v2 = (e2 < m) ? Ts2[(size_t)r2 * 16 + d4] : z;
            uint2 v3 = (e3 < m) ? Ts2[(size_t)r3 * 16 + d4] : z;
            a0 += bflo(v0.x) + bflo(v1.x) + bflo(v2.x) + bflo(v3.x);
            a1 += bfhi(v0.x) + bfhi(v1.x) + bfhi(v2.x) + bfhi(v3.x);
            a2 += bflo(v0.y) + bflo(v1.y) + bflo(v2.y) + bflo(v3.y);
            a3 += bfhi(v0.y) + bfhi(v1.y) + bfhi(v2.y) + bfhi(v3.y);
        }
    }
    a0 += __shfl_xor(a0, 16); a0 += __shfl_xor(a0, 32);
    a1 += __shfl_xor(a1, 16); a1 += __shfl_xor(a1, 32);
    a2 += __shfl_xor(a2, 16); a2 += __shfl_xor(a2, 32);
    a3 += __shfl_xor(a3, 16); a3 += __shfl_xor(a3, 32);
    if (lane < 16) {
        float dc = dinv[c];
        uint2 ur = Rs2[(size_t)c * 16 + d4];
        float h0 = fmaxf(fmaf(dc, a0, bflo(ur.x)), 0.0f);
        float h1 = fmaxf(fmaf(dc, a1, bfhi(ur.x)), 0.0f);
        float h2 = fmaxf(fmaf(dc, a2, bflo(ur.y)), 0.0f);
        float h3 = fmaxf(fmaf(dc, a3, bfhi(ur.y)), 0.0f);
        Hb2[(size_t)c * 16 + d4] = make_uint2(pack_bf16(h0, h1), pack_bf16(h2, h3));
    }
}

// ---------------- mean-pool over sorted batch (bf16x2 loads, half-wave/node) ----------------
__global__ __launch_bounds__(256) void pool_kernel(
    const uint32* __restrict__ Hb, const int* __restrict__ batch,
    float* __restrict__ pooled, float* __restrict__ cnt, int n) {
    __shared__ float sAcc[64 * 64];
    __shared__ float sCnt[64];
    int tid = threadIdx.x;
    for (int i = tid; i < 4096; i += 256) sAcc[i] = 0.0f;
    if (tid < 64) sCnt[tid] = 0.0f;
    __syncthreads();

    int w = tid >> 6, lane = tid & 63;
    int half = lane >> 5, d2 = lane & 31;
    int s = blockIdx.x * 256 + w * 64;
    int e = min(s + 64, n);
    float a0 = 0.0f, a1 = 0.0f, c = 0.0f;
    int gcur = -1;
    for (int i = s + half; i < e; i += 2) {
        int g = batch[i];
        if (g != gcur) {
            if (gcur >= 0) {
                atomicAdd(&sAcc[gcur * 64 + 2 * d2], a0);
                atomicAdd(&sAcc[gcur * 64 + 2 * d2 + 1], a1);
                if (d2 == 0) atomicAdd(&sCnt[gcur], c);
            }
            gcur = g; a0 = 0.0f; a1 = 0.0f; c = 0.0f;
        }
        uint32 u = Hb[(size_t)i * 32 + d2];
        a0 += bflo(u);
        a1 += bfhi(u);
        c += 1.0f;
    }
    if (gcur >= 0) {
        atomicAdd(&sAcc[gcur * 64 + 2 * d2], a0);
        atomicAdd(&sAcc[gcur * 64 + 2 * d2 + 1], a1);
        if (d2 == 0) atomicAdd(&sCnt[gcur], c);
    }
    __syncthreads();
    for (int i = tid; i < 4096; i += 256) {
        float v = sAcc[i];
        if (v != 0.0f) atomicAdd(&pooled[i], v);
    }
    if (tid < 64) {
        float v = sCnt[tid];
        if (v != 0.0f) atomicAdd(&cnt[tid], v);
    }
}

// ---------------- out[g,o] = (pooled[g,:]/max(cnt,1)) @ fcw + fcb ----------------
__global__ void final_fc(const float* __restrict__ pooled, const float* __restrict__ cnt,
                         const float* __restrict__ fcw, const float* __restrict__ fcb,
                         float* __restrict__ out) {
    int idx = blockIdx.x * 256 + threadIdx.x;
    if (idx >= 64 * 32) return;
    int g = idx >> 5, o = idx & 31;
    float c = fmaxf(cnt[g], 1.0f);
    float acc = 0.0f;
#pragma unroll
    for (int k = 0; k < 64; ++k) acc = fmaf(pooled[g * 64 + k], fcw[k * 32 + o], acc);
    out[idx] = acc / c + fcb[o];
}

extern "C" void kernel_launch(void* const* d_in, const int* in_sizes, int n_in,
                              void* d_out, int out_size, void* d_ws, size_t ws_size,
                              hipStream_t stream) {
    const float* x       = (const float*)d_in[0];
    const int*   eidx    = (const int*)d_in[1];
    const int*   batch   = (const int*)d_in[2];
    const float* w1_init = (const float*)d_in[3];
    const float* w1_root = (const float*)d_in[4];
    const float* b1      = (const float*)d_in[5];
    const float* w2_init = (const float*)d_in[6];
    const float* w2_root = (const float*)d_in[7];
    const float* b2      = (const float*)d_in[8];
    const float* fc_w    = (const float*)d_in[9];
    const float* fc_b    = (const float*)d_in[10];
    float* out = (float*)d_out;

    const int N = in_sizes[0] / 64;
    const int E = in_sizes[1] / 2;
    const int* row = eidx;
    const int* col = eidx + E;

    const int B = (N + NB - 1) / NB;  // 391 buckets

    // workspace (4-byte units, 16B-aligned chunks):
    // bpack(B*CAP) | es(B*CAP) | bcnt(MAXB) | pooled(4096) | cnt(64)
    // | nstart(N) | ndeg(N) | dinv(N) | wt(16384 uints = 8 mats * 4096 ushorts)
    // | Ts(N*32) | Rs(N*32) | Hb(N*32)
    uint32* bpack = (uint32*)d_ws;
    int*   es     = (int*)(bpack + (size_t)B * CAP);
    int*   bcnt   = es + (size_t)B * CAP;
    float* pooled = (float*)(bcnt + MAXB);
    float* cnt    = pooled + 64 * 64;
    int*   nstart = (int*)(cnt + 64);
    int*   ndeg   = nstart + N;
    float* dinv   = (float*)(ndeg + N);
    uint32* wtU   = (uint32*)(dinv + N);            // 16384 uints (64 KB)
    uint32* Ts    = wtU + 16384;                    // N*32
    uint32* Rs    = Ts + (size_t)N * 32;            // N*32
    uint32* Hb    = Rs + (size_t)N * 32;            // N*32
    ushort16* wt  = (ushort16*)wtU;

    hipMemsetAsync(bcnt, 0, (size_t)(MAXB + 64 * 64 + 64) * sizeof(int), stream);

    // CSR build + weight prep (shared by both layers)
    wprep_kernel<<<(8 * 4096 + 255) / 256, 256, 0, stream>>>(w1_init, w1_root, w2_init, w2_root, wt);
    bucket_kernel<<<(E + P1_CHUNK - 1) / P1_CHUNK, 256, 0, stream>>>(row, col, bpack, bcnt, E);
    csr_kernel<<<B, 1024, 0, stream>>>(bpack, bcnt, es, nstart, ndeg, dinv, N);

    // layer 1 (f32 input); wt = mats 0..3 (layer-1 init_hi/init_lo/root_hi/root_lo)
    gemm_mfma<<<(N + 63) / 64, 256, 0, stream>>>(x, wt, b1, dinv,
                                                 (ushort16*)Ts, (ushort16*)Rs, N, 1);
    gather_fused<<<(N + 3) / 4, 256, 0, stream>>>((const uint2*)Ts, (const uint2*)Rs,
                                                  es, nstart, ndeg, dinv, (uint2*)Hb, N);

    // layer 2 (bf16 input); wt + 4*4096 ushorts = mats 4..7 (layer-2 weights)
    gemm_mfma<<<(N + 63) / 64, 256, 0, stream>>>(Hb, wt + (size_t)4 * 4096, b2, dinv,
                                                 (ushort16*)Ts, (ushort16*)Rs, N, 0);
    gather_fused<<<(N + 3) / 4, 256, 0, stream>>>((const uint2*)Ts, (const uint2*)Rs,
                                                  es, nstart, ndeg, dinv, (uint2*)Hb, N);

    // pool + FC
    pool_kernel<<<(N + 255) / 256, 256, 0, stream>>>(Hb, batch, pooled, cnt, N);
    final_fc<<<(64 * 32 + 255) / 256, 256, 0, stream>>>(pooled, cnt, fc_w, fc_b, out);
}